// Round 1
// baseline (261.152 us; speedup 1.0000x reference)
//
#include <hip/hip_runtime.h>

typedef __bf16 bf16;
typedef __attribute__((ext_vector_type(8))) __bf16 bf16x8;
typedef __attribute__((ext_vector_type(4))) __bf16 bf16x4;
typedef __attribute__((ext_vector_type(4))) float f32x4;

typedef __attribute__((address_space(1))) const void GvPtr;
typedef __attribute__((address_space(3))) void LdsPtr;

__device__ __forceinline__ void gload_lds16(const void* g, void* l) {
    __builtin_amdgcn_global_load_lds((GvPtr*)g, (LdsPtr*)l, 16, 0, 0);
}

// ---------------------------------------------------------------------------
// ONE prep kernel: dtype-detect + X convert + weight transpose + bias + rowsum zero.
__global__ __launch_bounds__(256) void prep(
    const void* __restrict__ X,
    const void* __restrict__ Wq, const void* __restrict__ Wk,
    const void* __restrict__ Wv,
    const void* __restrict__ bq, const void* __restrict__ bk,
    const void* __restrict__ bv,
    bf16* __restrict__ Xb, bf16* __restrict__ wt, bf16* __restrict__ bb,
    float* __restrict__ rowsum)
{
    __shared__ int sflag;
    __shared__ bf16 t[32][33];
    const int tid = threadIdx.x;

    if (tid < 64) {
        const unsigned short* H = (const unsigned short*)X;
        int insane = 0;
        for (int i = tid; i < 128; i += 64) {
            int e = (H[2 * i] >> 7) & 0xFF;
            insane += (e >= 107 && e <= 131) ? 0 : 1;
        }
        #pragma unroll
        for (int off = 32; off > 0; off >>= 1)
            insane += __shfl_down(insane, off, 64);
        if (tid == 0) sflag = (insane >= 32) ? 1 : 0;
    }
    __syncthreads();
    const bool isf32 = (sflag != 0);

    const long b = blockIdx.x;
    if (b < 4096) {                       // X: 8M elems -> bf16, 8/thread
        long i = b * 256 + tid;
        if (isf32) {
            const float4* s = (const float4*)X;
            float4 a = s[2 * i], c = s[2 * i + 1];
            bf16x8 o;
            o[0] = (bf16)a.x; o[1] = (bf16)a.y; o[2] = (bf16)a.z; o[3] = (bf16)a.w;
            o[4] = (bf16)c.x; o[5] = (bf16)c.y; o[6] = (bf16)c.z; o[7] = (bf16)c.w;
            ((bf16x8*)Xb)[i] = o;
        } else {
            ((uint4*)Xb)[i] = ((const uint4*)X)[i];
        }
    } else if (b < 7168) {                // W transpose: [1024,1024] -> ^T
        const int wi = (int)((b - 4096) >> 10);
        const int id = (int)((b - 4096) & 1023);
        const void* src = (wi == 0) ? Wq : (wi == 1) ? Wk : Wv;
        bf16* dst = wt + (long)wi * 1024 * 1024;
        const int c0 = (id & 31) * 32, r0 = (id >> 5) * 32;
        const int tc = tid & 31, tr = tid >> 5;
        #pragma unroll
        for (int i = 0; i < 4; i++) {
            long idx = (long)(r0 + tr + i * 8) * 1024 + c0 + tc;
            t[tr + i * 8][tc] = isf32 ? (bf16)((const float*)src)[idx]
                                      : ((const bf16*)src)[idx];
        }
        __syncthreads();
        #pragma unroll
        for (int i = 0; i < 4; i++)
            dst[(long)(c0 + tr + i * 8) * 1024 + r0 + tc] = t[tc][tr + i * 8];
    } else if (b < 7180) {                // biases: 3 x 1024
        const int bi = (int)(b - 7168);
        const int wi = bi >> 2;
        const void* src = (wi == 0) ? bq : (wi == 1) ? bk : bv;
        const long i = (bi & 3) * 256 + tid;
        bb[wi * 1024 + i] = isf32 ? (bf16)((const float*)src)[i]
                                  : ((const bf16*)src)[i];
    } else {                              // rowsum zero: 8192 f32, 8 blocks
        const long i = (b - 7180) * 256 + tid;   // one float4 per thread
        ((float4*)rowsum)[i] = make_float4(0.f, 0.f, 0.f, 0.f);
    }
}

// ---------------------------------------------------------------------------
// 256x256-tile, BK=64, 8-wave (2Mx4N, wave tile 128x64), 8-PHASE schedule.
// C = scale*(A.B^T)+bias (or p'=exp(scale*.)+rowsum with EXPSUM; V->vt with VSPLIT).
//
// LDS: As[2][256x64] + Bs[2][256x64] = 128 KiB -> 1 block/CU, 2 waves/SIMD.
// Staging: issue = 64 rows x 64 cols via 2x global_load_lds(16B)/thread-group;
//   thread t -> row t>>3, chunk (t&7); global col chunk rotated by row mod 8
//   (same proven conflict-free chunk-rotation as the previous kernel: phys
//   chunk p at LDS row r holds global chunk (p - r) & 7; reads use
//   (ks*4 + quad + row) & 7). SQ_LDS_BANK_CONFLICT measured 0 on this scheme.
//
// Per iteration = 2 K-tiles, 8 phases. buf0 consumed ph1-4 (quadrant q per
// phase; B-frags read once at ph1 into regs), buf1 consumed ph5-8.
// Stage slots (half-tile = 128 rows = 2 issues):
//   ph1: buf1.A0 <- T(2i+1)   ph5: buf0.A0 <- T(2i+2)
//   ph2: buf1.A1 <- T(2i+1)   ph6: buf0.A1 <- T(2i+2)
//   ph3: buf0.B0 <- T(2i+2)   ph7: buf1.B0 <- T(2i+3)
//   ph4: buf0.B1 <- T(2i+2)   ph8: buf1.B1 <- T(2i+3)
// WAR: each stage lands >=2 barriers after the last ds_read of the region it
// overwrites (B read once ph1/ph5 into regs; A quadrant q read only ph q).
// RAW: s_waitcnt vmcnt(4) before trailing barrier of ph4 (retires buf1's 8
// loads: prev ph7/8 + ph1/2) and ph8 (retires buf0's 8 loads: ph3/4 + ph5/6).
// Never vmcnt(0) in steady state; last iteration degrades ph4 wait to vmcnt(0)
// and skips dead stages. sched_barrier(0) after each trailing s_barrier pins
// next-phase loads/stages from hoisting across the sync point.
template <bool HAS_BIAS, bool VSPLIT, bool EXPSUM>
__global__ __launch_bounds__(512, 2) void gemm_bt256(
    const bf16* __restrict__ A, const bf16* __restrict__ B,
    void* __restrict__ Cv, const bf16* __restrict__ bias,
    bf16* __restrict__ vt, float* __restrict__ rowsum,
    int K, long lda, long ldb, long ldc, float scale,
    long strideA, long strideB, long strideC)
{
    __shared__ bf16 As[2][256 * 64];   // 64 KB
    __shared__ bf16 Bs[2][256 * 64];   // 64 KB

    const int tid  = threadIdx.x;
    const int wave = tid >> 6;
    const int lane = tid & 63;
    const int r16  = lane & 15;
    const int quad = lane >> 4;

    const long z = blockIdx.z;
    A += z * strideA;
    B += z * strideB;

    const int tX = gridDim.x;
    const int pid = blockIdx.y * tX + blockIdx.x;
    const int groupSize = 8 * tX;
    const int gid = pid / groupSize;
    const int rem = pid % groupSize;
    const int tileM = (gid * 8 + (rem & 7)) * 256;
    const int tileN = (rem >> 3) * 256;

    const int waveM = (wave >> 2) * 128;   // 2 wave rows
    const int waveN = (wave & 3) * 64;     // 4 wave cols

    const int rS = tid >> 3;               // 0..63
    const int cOff = (((tid & 7) - (tid >> 3)) & 7) * 8;
    const bf16* Ab = A + (long)(tileM + rS) * lda + cOff;
    const bf16* Bb = B + (long)(tileN + rS) * ldb + cOff;

    // swizzled read chunks: (ks*4 + quad + row)&7 with row==r16 (mod 8)
    const int ch[2] = { ((quad + r16) & 7) * 8, ((quad + r16 + 4) & 7) * 8 };

#define STAGE_A(buf, h, t) do {                                               \
    const bf16* p_ = Ab + (long)((h) * 128) * lda + ((long)(t) << 6);         \
    gload_lds16(p_,            &As[buf][tid * 8 + (h) * 8192]);               \
    gload_lds16(p_ + 64 * lda, &As[buf][tid * 8 + (h) * 8192 + 4096]);        \
} while (0)
#define STAGE_B(buf, h, t) do {                                               \
    const bf16* p_ = Bb + (long)((h) * 128) * ldb + ((long)(t) << 6);         \
    gload_lds16(p_,            &Bs[buf][tid * 8 + (h) * 8192]);               \
    gload_lds16(p_ + 64 * ldb, &Bs[buf][tid * 8 + (h) * 8192 + 4096]);        \
} while (0)

    f32x4 acc[8][4] = {};

    // prologue: T0 fully into buf0, T1.B into buf1 (12 loads)
    STAGE_A(0, 0, 0); STAGE_A(0, 1, 0);
    STAGE_B(0, 0, 0); STAGE_B(0, 1, 0);
    STAGE_B(1, 0, 1); STAGE_B(1, 1, 1);
    asm volatile("s_waitcnt vmcnt(4)" ::: "memory");   // T0 landed; T1.B in flight
    __builtin_amdgcn_s_barrier();
    __builtin_amdgcn_sched_barrier(0);

    const int NI = K >> 7;                 // 2 K-tiles per iteration
    for (int i = 0; i < NI; ++i) {
        const int t1 = 2 * i + 1;
        const int t2 = 2 * i + 2;
        const int t3 = 2 * i + 3;
        const bool notlast = (i != NI - 1);

        #pragma unroll
        for (int h8 = 0; h8 < 2; ++h8) {   // h8=0: buf0 (ph1-4); h8=1: buf1 (ph5-8)
            bf16x8 bf[4][2];
            #pragma unroll
            for (int q = 0; q < 4; ++q) {
                bf16x8 af[2][2];
                if (q == 0) {
                    #pragma unroll
                    for (int ni = 0; ni < 4; ++ni) {
                        const int ro = (waveN + ni * 16 + r16) << 6;
                        #pragma unroll
                        for (int ks = 0; ks < 2; ++ks)
                            bf[ni][ks] = *(const bf16x8*)&Bs[h8][ro + ch[ks]];
                    }
                }
                #pragma unroll
                for (int m2 = 0; m2 < 2; ++m2) {
                    const int ro = (waveM + (q * 2 + m2) * 16 + r16) << 6;
                    #pragma unroll
                    for (int ks = 0; ks < 2; ++ks)
                        af[m2][ks] = *(const bf16x8*)&As[h8][ro + ch[ks]];
                }
                // stage schedule (see header comment)
                if (h8 == 0) {
                    if (q == 0)      STAGE_A(1, 0, t1);
                    else if (q == 1) STAGE_A(1, 1, t1);
                    else if (q == 2) { if (notlast) STAGE_B(0, 0, t2); }
                    else             { if (notlast) STAGE_B(0, 1, t2); }
                } else if (notlast) {
                    if (q == 0)      STAGE_A(0, 0, t2);
                    else if (q == 1) STAGE_A(0, 1, t2);
                    else if (q == 2) STAGE_B(1, 0, t3);
                    else             STAGE_B(1, 1, t3);
                }
                __builtin_amdgcn_s_barrier();
                __builtin_amdgcn_s_setprio(1);
                #pragma unroll
                for (int ks = 0; ks < 2; ++ks)
                    #pragma unroll
                    for (int m2 = 0; m2 < 2; ++m2)
                        #pragma unroll
                        for (int ni = 0; ni < 4; ++ni)
                            acc[q * 2 + m2][ni] = __builtin_amdgcn_mfma_f32_16x16x32_bf16(
                                af[m2][ks], bf[ni][ks], acc[q * 2 + m2][ni], 0, 0, 0);
                __builtin_amdgcn_s_setprio(0);
                if (q == 3) {
                    if (h8 == 0) {
                        if (notlast) asm volatile("s_waitcnt vmcnt(4)" ::: "memory");
                        else         asm volatile("s_waitcnt vmcnt(0)" ::: "memory");
                    } else if (notlast) {
                        asm volatile("s_waitcnt vmcnt(4)" ::: "memory");
                    }
                }
                __builtin_amdgcn_s_barrier();
                __builtin_amdgcn_sched_barrier(0);
            }
        }
    }
#undef STAGE_A
#undef STAGE_B

    // C/D layout (m89/m91 verified): col = lane&15, row = quad*4 + r.
    const int crow0 = tileM + waveM + quad * 4;
    const int ccol0 = tileN + waveN + r16;

    if (EXPSUM) {
        float rs[8][4];
        #pragma unroll
        for (int mi = 0; mi < 8; ++mi)
            #pragma unroll
            for (int r = 0; r < 4; ++r) rs[mi][r] = 0.0f;
        #pragma unroll
        for (int ni = 0; ni < 4; ++ni) {
            const int col = ccol0 + ni * 16;
            #pragma unroll
            for (int mi = 0; mi < 8; ++mi) {
                #pragma unroll
                for (int r = 0; r < 4; ++r) {
                    const long row = crow0 + mi * 16 + r;
                    const float p = __expf(acc[mi][ni][r] * scale);
                    rs[mi][r] += p;
                    ((bf16*)Cv)[z * strideC + row * ldc + col] = (bf16)p;
                }
            }
        }
        #pragma unroll
        for (int mi = 0; mi < 8; ++mi) {
            #pragma unroll
            for (int r = 0; r < 4; ++r) {
                float s = rs[mi][r];
                s += __shfl_xor(s, 1, 64);
                s += __shfl_xor(s, 2, 64);
                s += __shfl_xor(s, 4, 64);
                s += __shfl_xor(s, 8, 64);
                if (r16 == 0)
                    atomicAdd(&rowsum[z * 2048 + crow0 + mi * 16 + r], s);
            }
        }
    } else if (VSPLIT && tileN >= 2048) {
        #pragma unroll
        for (int ni = 0; ni < 4; ++ni) {
            const int col = ccol0 + ni * 16;
            const float bv = HAS_BIAS ? (float)bias[col] : 0.0f;
            const long colp = col - 2048;
            #pragma unroll
            for (int mi = 0; mi < 8; ++mi) {
                const int grow = crow0 + mi * 16;
                const long bz = grow >> 11;
                const int srow = grow & 2047;
                bf16x4 o;
                #pragma unroll
                for (int r = 0; r < 4; ++r)
                    o[r] = (bf16)(acc[mi][ni][r] * scale + bv);
                *(bf16x4*)&vt[(bz << 21) + colp * 2048 + srow] = o;
            }
        }
    } else {
        #pragma unroll
        for (int ni = 0; ni < 4; ++ni) {
            const int col = ccol0 + ni * 16;
            const float bv = HAS_BIAS ? (float)bias[col] : 0.0f;
            #pragma unroll
            for (int mi = 0; mi < 8; ++mi) {
                #pragma unroll
                for (int r = 0; r < 4; ++r) {
                    const long row = crow0 + mi * 16 + r;
                    ((bf16*)Cv)[z * strideC + row * ldc + col] =
                        (bf16)(acc[mi][ni][r] * scale + bv);
                }
            }
        }
    }
}

// ---------------------------------------------------------------------------
// PV GEMM: 8 waves (512 thr), BK=128, 128x128 tile, wave tile 32x64.
// 64 KB LDS -> 2 blocks/CU = 16 waves/CU. out = (A.B^T) / rowsum[row].
// mod-16 chunk-rotation swizzle, j-invariant (32-row steps are 0 mod 16).
__global__ __launch_bounds__(512, 2) void gemm_pv(
    const bf16* __restrict__ A, const bf16* __restrict__ B,
    float* __restrict__ C, const float* __restrict__ rowsum,
    int K, long lda, long ldb, long ldc,
    long strideA, long strideB, long strideC)
{
    constexpr int BK = 128;
    __shared__ bf16 As[128 * BK];  // 32 KB
    __shared__ bf16 Bs[128 * BK];  // 32 KB

    const int tid  = threadIdx.x;
    const int wave = tid >> 6;
    const int lane = tid & 63;
    const int r16  = lane & 15;
    const int quad = lane >> 4;

    const long z = blockIdx.z;
    A += z * strideA;
    B += z * strideB;

    const int tX = gridDim.x;
    const int pid = blockIdx.y * tX + blockIdx.x;
    const int groupSize = 8 * tX;
    const int gid = pid / groupSize;
    const int rem = pid % groupSize;
    const int tileM = (gid * 8 + (rem & 7)) * 128;
    const int tileN = (rem >> 3) * 128;

    const int waveM = (wave >> 1) * 32;
    const int waveN = (wave & 1) * 64;

    const int rS = tid >> 4;                              // 0..31
    const int cOff = (((tid & 15) - (tid >> 4)) & 15) * 8;
    const bf16* Ag = A + (long)(tileM + rS) * lda + cOff;
    const bf16* Bg = B + (long)(tileN + rS) * ldb + cOff;

    f32x4 acc[2][4] = {};

    for (int k0 = 0; k0 < K; k0 += BK) {
        #pragma unroll
        for (int j = 0; j < 4; j++) {
            gload_lds16(Ag + (long)j * 32 * lda, &As[(tid + j * 512) * 8]);
            gload_lds16(Bg + (long)j * 32 * ldb, &Bs[(tid + j * 512) * 8]);
        }
        Ag += BK; Bg += BK;
        __syncthreads();

        #pragma unroll
        for (int ks = 0; ks < 4; ks++) {
            bf16x8 af[2], bfv[4];
            #pragma unroll
            for (int i = 0; i < 2; i++) {
                const int row = waveM + i * 16 + r16;
                af[i] = *(const bf16x8*)
                    &As[row * 128 + ((ks * 4 + quad + row) & 15) * 8];
            }
            #pragma unroll
            for (int i = 0; i < 4; i++) {
                const int row = waveN + i * 16 + r16;
                bfv[i] = *(const bf16x8*)
                    &Bs[row * 128 + ((ks * 4 + quad + row) & 15) * 8];
            }
            #pragma unroll
            for (int mi = 0; mi < 2; mi++)
                #pragma unroll
                for (int ni = 0; ni < 4; ni++)
                    acc[mi][ni] = __builtin_amdgcn_mfma_f32_16x16x32_bf16(
                        af[mi], bfv[ni], acc[mi][ni], 0, 0, 0);
        }
        __syncthreads();
    }

    const int crow0 = tileM + waveM + quad * 4;
    const int ccol0 = tileN + waveN + r16;
    float inv[2][4];
    #pragma unroll
    for (int mi = 0; mi < 2; mi++)
        #pragma unroll
        for (int r = 0; r < 4; r++)
            inv[mi][r] = 1.0f / rowsum[z * 2048 + crow0 + mi * 16 + r];
    #pragma unroll
    for (int ni = 0; ni < 4; ni++) {
        const int col = ccol0 + ni * 16;
        #pragma unroll
        for (int mi = 0; mi < 2; mi++)
            #pragma unroll
            for (int r = 0; r < 4; r++) {
                const long row = crow0 + mi * 16 + r;
                C[z * strideC + row * ldc + col] = acc[mi][ni][r] * inv[mi][r];
            }
    }
}

extern "C" void kernel_launch(void* const* d_in, const int* in_sizes, int n_in,
                              void* d_out, int out_size, void* d_ws, size_t ws_size,
                              hipStream_t stream) {
    constexpr int B = 4, S = 2048, D = 1024, N = 1024;
    constexpr long MS = (long)B * S;  // 8192

    const void* X  = d_in[0];
    const void* Wq = d_in[1];
    const void* bq = d_in[2];
    const void* Wk = d_in[3];
    const void* bk = d_in[4];
    const void* Wv = d_in[5];
    const void* bv = d_in[6];

    // workspace layout (~120 MB)
    char* w = (char*)d_ws;
    bf16*  Xb = (bf16*)w;                w += MS * D * sizeof(bf16);          // 16 MB
    bf16*  wt = (bf16*)w;                w += 3L * D * N * sizeof(bf16);      // 6 MB
    bf16*  bb = (bf16*)w;                w += 3L * N * sizeof(bf16) + 512;
    float* rowsum = (float*)w;           w += MS * sizeof(float);             // 32 KB
    bf16*  qkv = (bf16*)w;               w += MS * 3L * N * sizeof(bf16);     // 48 MB
    bf16*  vt = (bf16*)w;                w += MS * N * sizeof(bf16);          // 16 MB
    bf16*  sc = (bf16*)w;                                                    // 32 MB

    bf16* q = qkv;            // cols 0..1023 of [8192,3072]
    bf16* k = qkv + N;        // cols 1024..2047 (V cols go straight to vt)

    // 1) prep: detect + convert X/biases + transpose weights + zero rowsum
    prep<<<7188, 256, 0, stream>>>(X, Wq, Wk, Wv, bq, bk, bv, Xb, wt, bb, rowsum);

    // 2) fused QKV (256² 8-phase): q,k -> qkv; V -> vt transposed.
    //    12x32 = 384 blocks @ 1/CU.
    gemm_bt256<true, true, false><<<dim3(3 * N / 256, MS / 256, 1), 512, 0, stream>>>(
        Xb, wt, qkv, bb, vt, nullptr, D, D, D, 3L * N, 1.0f, 0, 0, 0);

    // 3) p' = exp(q.k^T / 32) -> bf16 sc, + atomic row sums
    //    (256² 8-phase: 8x8x4 = 256 blocks = exactly 1 round @ 1/CU)
    gemm_bt256<false, false, true><<<dim3(S / 256, S / 256, B), 512, 0, stream>>>(
        q, k, sc, nullptr, nullptr, rowsum, D, 3L * N, 3L * N, S, 0.03125f,
        (long)S * 3 * N, (long)S * 3 * N, (long)S * S);

    // 4) out = (p' . vt^T) / rowsum -> f32 d_out (8-wave BK=128 PV)
    gemm_pv<<<dim3(N / 128, S / 128, B), 512, 0, stream>>>(
        sc, vt, (float*)d_out, rowsum, S, S, S, N,
        (long)S * S, (long)N * S, (long)S * N);
}

// Round 2
// 245.697 us; speedup vs baseline: 1.0629x; 1.0629x over previous
//
#include <hip/hip_runtime.h>

typedef __bf16 bf16;
typedef __attribute__((ext_vector_type(8))) __bf16 bf16x8;
typedef __attribute__((ext_vector_type(4))) __bf16 bf16x4;
typedef __attribute__((ext_vector_type(4))) float f32x4;

typedef __attribute__((address_space(1))) const void GvPtr;
typedef __attribute__((address_space(3))) void LdsPtr;

__device__ __forceinline__ void gload_lds16(const void* g, void* l) {
    __builtin_amdgcn_global_load_lds((GvPtr*)g, (LdsPtr*)l, 16, 0, 0);
}

// ---------------------------------------------------------------------------
// ONE prep kernel: dtype-detect + X convert + weight transpose + bias + rowsum zero.
__global__ __launch_bounds__(256) void prep(
    const void* __restrict__ X,
    const void* __restrict__ Wq, const void* __restrict__ Wk,
    const void* __restrict__ Wv,
    const void* __restrict__ bq, const void* __restrict__ bk,
    const void* __restrict__ bv,
    bf16* __restrict__ Xb, bf16* __restrict__ wt, bf16* __restrict__ bb,
    float* __restrict__ rowsum)
{
    __shared__ int sflag;
    __shared__ bf16 t[32][33];
    const int tid = threadIdx.x;

    if (tid < 64) {
        const unsigned short* H = (const unsigned short*)X;
        int insane = 0;
        for (int i = tid; i < 128; i += 64) {
            int e = (H[2 * i] >> 7) & 0xFF;
            insane += (e >= 107 && e <= 131) ? 0 : 1;
        }
        #pragma unroll
        for (int off = 32; off > 0; off >>= 1)
            insane += __shfl_down(insane, off, 64);
        if (tid == 0) sflag = (insane >= 32) ? 1 : 0;
    }
    __syncthreads();
    const bool isf32 = (sflag != 0);

    const long b = blockIdx.x;
    if (b < 4096) {                       // X: 8M elems -> bf16, 8/thread
        long i = b * 256 + tid;
        if (isf32) {
            const float4* s = (const float4*)X;
            float4 a = s[2 * i], c = s[2 * i + 1];
            bf16x8 o;
            o[0] = (bf16)a.x; o[1] = (bf16)a.y; o[2] = (bf16)a.z; o[3] = (bf16)a.w;
            o[4] = (bf16)c.x; o[5] = (bf16)c.y; o[6] = (bf16)c.z; o[7] = (bf16)c.w;
            ((bf16x8*)Xb)[i] = o;
        } else {
            ((uint4*)Xb)[i] = ((const uint4*)X)[i];
        }
    } else if (b < 7168) {                // W transpose: [1024,1024] -> ^T
        const int wi = (int)((b - 4096) >> 10);
        const int id = (int)((b - 4096) & 1023);
        const void* src = (wi == 0) ? Wq : (wi == 1) ? Wk : Wv;
        bf16* dst = wt + (long)wi * 1024 * 1024;
        const int c0 = (id & 31) * 32, r0 = (id >> 5) * 32;
        const int tc = tid & 31, tr = tid >> 5;
        #pragma unroll
        for (int i = 0; i < 4; i++) {
            long idx = (long)(r0 + tr + i * 8) * 1024 + c0 + tc;
            t[tr + i * 8][tc] = isf32 ? (bf16)((const float*)src)[idx]
                                      : ((const bf16*)src)[idx];
        }
        __syncthreads();
        #pragma unroll
        for (int i = 0; i < 4; i++)
            dst[(long)(c0 + tr + i * 8) * 1024 + r0 + tc] = t[tc][tr + i * 8];
    } else if (b < 7180) {                // biases: 3 x 1024
        const int bi = (int)(b - 7168);
        const int wi = bi >> 2;
        const void* src = (wi == 0) ? bq : (wi == 1) ? bk : bv;
        const long i = (bi & 3) * 256 + tid;
        bb[wi * 1024 + i] = isf32 ? (bf16)((const float*)src)[i]
                                  : ((const bf16*)src)[i];
    } else {                              // rowsum zero: 8192 f32, 8 blocks
        const long i = (b - 7180) * 256 + tid;   // one float4 per thread
        ((float4*)rowsum)[i] = make_float4(0.f, 0.f, 0.f, 0.f);
    }
}

// ---------------------------------------------------------------------------
// BK=64 GEMM: C = scale*(A.B^T)+bias (or p'=exp(scale*.) with EXPSUM).
// 128x128 tile, 16x16x32 bf16 MFMA, global_load_lds w=16, GROUP_M=8 swizzle,
// mod-8 LDS chunk-rotation (verified conflict-free R6-R8).
// WAVES=4: 256 thr, wave tile 64x64 (acc 4x4) -> 4 blocks/CU.
// WAVES=8: 512 thr, wave tile 32x64 (acc 2x4) -> 2 blocks/CU = 16 waves/CU,
//   exact 3-round schedule on the 1536-block QKV grid (R8 PV validated the
//   8-wave>4-wave residency effect).
template <bool HAS_BIAS, bool OUT_F32, int WAVES, bool VSPLIT, bool EXPSUM>
__global__ __launch_bounds__(WAVES * 64, 4) void gemm_bt(
    const bf16* __restrict__ A, const bf16* __restrict__ B,
    void* __restrict__ Cv, const bf16* __restrict__ bias,
    bf16* __restrict__ vt, float* __restrict__ rowsum,
    int K, long lda, long ldb, long ldc, float scale,
    long strideA, long strideB, long strideC)
{
    constexpr int BK = 64;
    constexpr int MI = (WAVES == 4) ? 4 : 2;
    constexpr int NCH = (WAVES == 4) ? 4 : 2;     // gload issues per matrix
    constexpr int RSTEP = WAVES * 8;              // rows per issue
    constexpr int LSTEP = WAVES * 64 * 8;         // LDS elems per issue

    __shared__ bf16 As[128 * BK];  // 16 KB
    __shared__ bf16 Bs[128 * BK];  // 16 KB

    const int tid  = threadIdx.x;
    const int wave = tid >> 6;
    const int lane = tid & 63;
    const int r16  = lane & 15;
    const int quad = lane >> 4;

    const long z = blockIdx.z;
    A += z * strideA;
    B += z * strideB;

    const int tX = gridDim.x;
    const int pid = blockIdx.y * tX + blockIdx.x;
    const int groupSize = 8 * tX;
    const int gid = pid / groupSize;
    const int rem = pid % groupSize;
    const int tileM = (gid * 8 + (rem & 7)) * 128;
    const int tileN = (rem >> 3) * 128;

    const int waveM = (wave >> 1) * ((WAVES == 4) ? 64 : 32);
    const int waveN = (wave & 1) * 64;

    // Swizzled staging: phys slot p = tid + j*(WAVES*64); row = p>>3; logical
    // chunk c = ((p&7) - row) & 7, j-invariant (RSTEP is 0 mod 8).
    const int rS = tid >> 3;
    const int cOff = (((tid & 7) - (tid >> 3)) & 7) * 8;
    const bf16* Ag[NCH]; const bf16* Bg[NCH];
    #pragma unroll
    for (int j = 0; j < NCH; j++) {
        Ag[j] = A + (long)(tileM + rS + j * RSTEP) * lda + cOff;
        Bg[j] = B + (long)(tileN + rS + j * RSTEP) * ldb + cOff;
    }

    f32x4 acc[MI][4] = {};

    for (int k0 = 0; k0 < K; k0 += BK) {
        #pragma unroll
        for (int j = 0; j < NCH; j++) {
            gload_lds16(Ag[j], &As[tid * 8 + j * LSTEP]);
            gload_lds16(Bg[j], &Bs[tid * 8 + j * LSTEP]);
            Ag[j] += BK; Bg[j] += BK;
        }
        __syncthreads();

        #pragma unroll
        for (int ks = 0; ks < 2; ks++) {
            bf16x8 af[MI], bfv[4];
            #pragma unroll
            for (int i = 0; i < MI; i++) {
                const int row = waveM + i * 16 + r16;
                af[i] = *(const bf16x8*)
                    &As[row * 64 + ((ks * 4 + quad + row) & 7) * 8];
            }
            #pragma unroll
            for (int i = 0; i < 4; i++) {
                const int row = waveN + i * 16 + r16;
                bfv[i] = *(const bf16x8*)
                    &Bs[row * 64 + ((ks * 4 + quad + row) & 7) * 8];
            }
            #pragma unroll
            for (int mi = 0; mi < MI; mi++)
                #pragma unroll
                for (int ni = 0; ni < 4; ni++)
                    acc[mi][ni] = __builtin_amdgcn_mfma_f32_16x16x32_bf16(
                        af[mi], bfv[ni], acc[mi][ni], 0, 0, 0);
        }
        __syncthreads();
    }

    // C/D layout (m89/m91 verified): col = lane&15, row = quad*4 + r.
    const int crow0 = tileM + waveM + quad * 4;
    const int ccol0 = tileN + waveN + r16;

    if (EXPSUM) {
        float rs[MI][4];
        #pragma unroll
        for (int mi = 0; mi < MI; mi++)
            #pragma unroll
            for (int r = 0; r < 4; r++) rs[mi][r] = 0.0f;
        #pragma unroll
        for (int ni = 0; ni < 4; ni++) {
            const int col = ccol0 + ni * 16;
            #pragma unroll
            for (int mi = 0; mi < MI; mi++) {
                #pragma unroll
                for (int r = 0; r < 4; r++) {
                    const long row = crow0 + mi * 16 + r;
                    const float p = __expf(acc[mi][ni][r] * scale);
                    rs[mi][r] += p;
                    ((bf16*)Cv)[z * strideC + row * ldc + col] = (bf16)p;
                }
            }
        }
        #pragma unroll
        for (int mi = 0; mi < MI; mi++) {
            #pragma unroll
            for (int r = 0; r < 4; r++) {
                float s = rs[mi][r];
                s += __shfl_xor(s, 1, 64);
                s += __shfl_xor(s, 2, 64);
                s += __shfl_xor(s, 4, 64);
                s += __shfl_xor(s, 8, 64);
                if (r16 == 0)
                    atomicAdd(&rowsum[z * 2048 + crow0 + mi * 16 + r], s);
            }
        }
    } else if (VSPLIT && tileN >= 2048) {
        #pragma unroll
        for (int ni = 0; ni < 4; ni++) {
            const int col = ccol0 + ni * 16;
            const float bv = HAS_BIAS ? (float)bias[col] : 0.0f;
            const long colp = col - 2048;
            #pragma unroll
            for (int mi = 0; mi < MI; mi++) {
                const int grow = crow0 + mi * 16;
                const long bz = grow >> 11;
                const int srow = grow & 2047;
                bf16x4 o;
                #pragma unroll
                for (int r = 0; r < 4; r++)
                    o[r] = (bf16)(acc[mi][ni][r] * scale + bv);
                *(bf16x4*)&vt[(bz << 21) + colp * 2048 + srow] = o;
            }
        }
    } else {
        #pragma unroll
        for (int ni = 0; ni < 4; ni++) {
            const int col = ccol0 + ni * 16;
            const float bv = HAS_BIAS ? (float)bias[col] : 0.0f;
            #pragma unroll
            for (int mi = 0; mi < MI; mi++) {
                #pragma unroll
                for (int r = 0; r < 4; r++) {
                    const long row = crow0 + mi * 16 + r;
                    const float val = acc[mi][ni][r] * scale + bv;
                    if (OUT_F32) ((float*)Cv)[z * strideC + row * ldc + col] = val;
                    else         ((bf16*)Cv)[z * strideC + row * ldc + col] = (bf16)val;
                }
            }
        }
    }
}

// ---------------------------------------------------------------------------
// PV GEMM: 8 waves (512 thr), BK=128, 128x128 tile, wave tile 32x64.
// 64 KB LDS -> 2 blocks/CU = 16 waves/CU. out = (A.B^T) / rowsum[row].
// mod-16 chunk-rotation swizzle, j-invariant (32-row steps are 0 mod 16).
__global__ __launch_bounds__(512, 2) void gemm_pv(
    const bf16* __restrict__ A, const bf16* __restrict__ B,
    float* __restrict__ C, const float* __restrict__ rowsum,
    int K, long lda, long ldb, long ldc,
    long strideA, long strideB, long strideC)
{
    constexpr int BK = 128;
    __shared__ bf16 As[128 * BK];  // 32 KB
    __shared__ bf16 Bs[128 * BK];  // 32 KB

    const int tid  = threadIdx.x;
    const int wave = tid >> 6;
    const int lane = tid & 63;
    const int r16  = lane & 15;
    const int quad = lane >> 4;

    const long z = blockIdx.z;
    A += z * strideA;
    B += z * strideB;

    const int tX = gridDim.x;
    const int pid = blockIdx.y * tX + blockIdx.x;
    const int groupSize = 8 * tX;
    const int gid = pid / groupSize;
    const int rem = pid % groupSize;
    const int tileM = (gid * 8 + (rem & 7)) * 128;
    const int tileN = (rem >> 3) * 128;

    const int waveM = (wave >> 1) * 32;
    const int waveN = (wave & 1) * 64;

    const int rS = tid >> 4;                              // 0..31
    const int cOff = (((tid & 15) - (tid >> 4)) & 15) * 8;
    const bf16* Ag = A + (long)(tileM + rS) * lda + cOff;
    const bf16* Bg = B + (long)(tileN + rS) * ldb + cOff;

    f32x4 acc[2][4] = {};

    for (int k0 = 0; k0 < K; k0 += BK) {
        #pragma unroll
        for (int j = 0; j < 4; j++) {
            gload_lds16(Ag + (long)j * 32 * lda, &As[(tid + j * 512) * 8]);
            gload_lds16(Bg + (long)j * 32 * ldb, &Bs[(tid + j * 512) * 8]);
        }
        Ag += BK; Bg += BK;
        __syncthreads();

        #pragma unroll
        for (int ks = 0; ks < 4; ks++) {
            bf16x8 af[2], bfv[4];
            #pragma unroll
            for (int i = 0; i < 2; i++) {
                const int row = waveM + i * 16 + r16;
                af[i] = *(const bf16x8*)
                    &As[row * 128 + ((ks * 4 + quad + row) & 15) * 8];
            }
            #pragma unroll
            for (int i = 0; i < 4; i++) {
                const int row = waveN + i * 16 + r16;
                bfv[i] = *(const bf16x8*)
                    &Bs[row * 128 + ((ks * 4 + quad + row) & 15) * 8];
            }
            #pragma unroll
            for (int mi = 0; mi < 2; mi++)
                #pragma unroll
                for (int ni = 0; ni < 4; ni++)
                    acc[mi][ni] = __builtin_amdgcn_mfma_f32_16x16x32_bf16(
                        af[mi], bfv[ni], acc[mi][ni], 0, 0, 0);
        }
        __syncthreads();
    }

    const int crow0 = tileM + waveM + quad * 4;
    const int ccol0 = tileN + waveN + r16;
    float inv[2][4];
    #pragma unroll
    for (int mi = 0; mi < 2; mi++)
        #pragma unroll
        for (int r = 0; r < 4; r++)
            inv[mi][r] = 1.0f / rowsum[z * 2048 + crow0 + mi * 16 + r];
    #pragma unroll
    for (int ni = 0; ni < 4; ni++) {
        const int col = ccol0 + ni * 16;
        #pragma unroll
        for (int mi = 0; mi < 2; mi++)
            #pragma unroll
            for (int r = 0; r < 4; r++) {
                const long row = crow0 + mi * 16 + r;
                C[z * strideC + row * ldc + col] = acc[mi][ni][r] * inv[mi][r];
            }
    }
}

extern "C" void kernel_launch(void* const* d_in, const int* in_sizes, int n_in,
                              void* d_out, int out_size, void* d_ws, size_t ws_size,
                              hipStream_t stream) {
    constexpr int B = 4, S = 2048, D = 1024, N = 1024;
    constexpr long MS = (long)B * S;  // 8192

    const void* X  = d_in[0];
    const void* Wq = d_in[1];
    const void* bq = d_in[2];
    const void* Wk = d_in[3];
    const void* bk = d_in[4];
    const void* Wv = d_in[5];
    const void* bv = d_in[6];

    // workspace layout (~120 MB)
    char* w = (char*)d_ws;
    bf16*  Xb = (bf16*)w;                w += MS * D * sizeof(bf16);          // 16 MB
    bf16*  wt = (bf16*)w;                w += 3L * D * N * sizeof(bf16);      // 6 MB
    bf16*  bb = (bf16*)w;                w += 3L * N * sizeof(bf16) + 512;
    float* rowsum = (float*)w;           w += MS * sizeof(float);             // 32 KB
    bf16*  qkv = (bf16*)w;               w += MS * 3L * N * sizeof(bf16);     // 48 MB
    bf16*  vt = (bf16*)w;                w += MS * N * sizeof(bf16);          // 16 MB
    bf16*  sc = (bf16*)w;                                                    // 32 MB

    bf16* q = qkv;            // cols 0..1023 of [8192,3072]
    bf16* k = qkv + N;        // cols 1024..2047 (V cols go straight to vt)

    // 1) prep: detect + convert X/biases + transpose weights + zero rowsum
    prep<<<7188, 256, 0, stream>>>(X, Wq, Wk, Wv, bq, bk, bv, Xb, wt, bb, rowsum);

    // 2) fused QKV (8-wave blocks): q,k -> qkv; V -> vt transposed.
    //    1536 blocks @ 2/CU = exact 3 rounds, 16 waves/CU.
    gemm_bt<true, false, 8, true, false><<<dim3(3 * N / 128, MS / 128, 1), 512, 0, stream>>>(
        Xb, wt, qkv, bb, vt, nullptr, D, D, D, 3L * N, 1.0f, 0, 0, 0);

    // 3) p' = exp(q.k^T / 32) -> bf16 sc, + atomic row sums (4-wave:
    //    1024 blocks @ 4/CU = exactly 1 round)
    gemm_bt<false, false, 4, false, true><<<dim3(S / 128, S / 128, B), 256, 0, stream>>>(
        q, k, sc, nullptr, nullptr, rowsum, D, 3L * N, 3L * N, S, 0.03125f,
        (long)S * 3 * N, (long)S * 3 * N, (long)S * S);

    // 4) out = (p' . vt^T) / rowsum -> f32 d_out (8-wave BK=128 PV)
    gemm_pv<<<dim3(N / 128, S / 128, B), 512, 0, stream>>>(
        sc, vt, (float*)d_out, rowsum, S, S, S, N,
        (long)S * S, (long)N * S, (long)S * N);
}

// Round 3
// 240.417 us; speedup vs baseline: 1.0862x; 1.0220x over previous
//
#include <hip/hip_runtime.h>

typedef __bf16 bf16;
typedef __attribute__((ext_vector_type(8))) __bf16 bf16x8;
typedef __attribute__((ext_vector_type(4))) __bf16 bf16x4;
typedef __attribute__((ext_vector_type(4))) float f32x4;

typedef __attribute__((address_space(1))) const void GvPtr;
typedef __attribute__((address_space(3))) void LdsPtr;

__device__ __forceinline__ void gload_lds16(const void* g, void* l) {
    __builtin_amdgcn_global_load_lds((GvPtr*)g, (LdsPtr*)l, 16, 0, 0);
}

// XCD-aware chunked remap (T1, m157/m192): dispatch id round-robins over the
// 8 XCDs (xcd = pid0 & 7 when per-z grid size % 8 == 0 -- true for all our
// grids: 1536 / 256 / 128). Remap so each XCD owns a CONTIGUOUS pid chunk;
// composed with the GROUP_M=8 decomposition this gives per-XCD working sets
// of 3-8 MB (vs ~22 MB XCD-oblivious), turning tile loads into L2 hits and
// shortening the vmcnt(0) drain that is this structure's stall.
__device__ __forceinline__ int xcd_remap(int pid0, int nwg) {
    return (pid0 & 7) * (nwg >> 3) + (pid0 >> 3);
}

// ---------------------------------------------------------------------------
// ONE prep kernel: dtype-detect + X convert + weight transpose + bias + rowsum zero.
__global__ __launch_bounds__(256) void prep(
    const void* __restrict__ X,
    const void* __restrict__ Wq, const void* __restrict__ Wk,
    const void* __restrict__ Wv,
    const void* __restrict__ bq, const void* __restrict__ bk,
    const void* __restrict__ bv,
    bf16* __restrict__ Xb, bf16* __restrict__ wt, bf16* __restrict__ bb,
    float* __restrict__ rowsum)
{
    __shared__ int sflag;
    __shared__ bf16 t[32][33];
    const int tid = threadIdx.x;

    if (tid < 64) {
        const unsigned short* H = (const unsigned short*)X;
        int insane = 0;
        for (int i = tid; i < 128; i += 64) {
            int e = (H[2 * i] >> 7) & 0xFF;
            insane += (e >= 107 && e <= 131) ? 0 : 1;
        }
        #pragma unroll
        for (int off = 32; off > 0; off >>= 1)
            insane += __shfl_down(insane, off, 64);
        if (tid == 0) sflag = (insane >= 32) ? 1 : 0;
    }
    __syncthreads();
    const bool isf32 = (sflag != 0);

    const long b = blockIdx.x;
    if (b < 4096) {                       // X: 8M elems -> bf16, 8/thread
        long i = b * 256 + tid;
        if (isf32) {
            const float4* s = (const float4*)X;
            float4 a = s[2 * i], c = s[2 * i + 1];
            bf16x8 o;
            o[0] = (bf16)a.x; o[1] = (bf16)a.y; o[2] = (bf16)a.z; o[3] = (bf16)a.w;
            o[4] = (bf16)c.x; o[5] = (bf16)c.y; o[6] = (bf16)c.z; o[7] = (bf16)c.w;
            ((bf16x8*)Xb)[i] = o;
        } else {
            ((uint4*)Xb)[i] = ((const uint4*)X)[i];
        }
    } else if (b < 7168) {                // W transpose: [1024,1024] -> ^T
        const int wi = (int)((b - 4096) >> 10);
        const int id = (int)((b - 4096) & 1023);
        const void* src = (wi == 0) ? Wq : (wi == 1) ? Wk : Wv;
        bf16* dst = wt + (long)wi * 1024 * 1024;
        const int c0 = (id & 31) * 32, r0 = (id >> 5) * 32;
        const int tc = tid & 31, tr = tid >> 5;
        #pragma unroll
        for (int i = 0; i < 4; i++) {
            long idx = (long)(r0 + tr + i * 8) * 1024 + c0 + tc;
            t[tr + i * 8][tc] = isf32 ? (bf16)((const float*)src)[idx]
                                      : ((const bf16*)src)[idx];
        }
        __syncthreads();
        #pragma unroll
        for (int i = 0; i < 4; i++)
            dst[(long)(c0 + tr + i * 8) * 1024 + r0 + tc] = t[tc][tr + i * 8];
    } else if (b < 7180) {                // biases: 3 x 1024
        const int bi = (int)(b - 7168);
        const int wi = bi >> 2;
        const void* src = (wi == 0) ? bq : (wi == 1) ? bk : bv;
        const long i = (bi & 3) * 256 + tid;
        bb[wi * 1024 + i] = isf32 ? (bf16)((const float*)src)[i]
                                  : ((const bf16*)src)[i];
    } else {                              // rowsum zero: 8192 f32, 8 blocks
        const long i = (b - 7180) * 256 + tid;   // one float4 per thread
        ((float4*)rowsum)[i] = make_float4(0.f, 0.f, 0.f, 0.f);
    }
}

// ---------------------------------------------------------------------------
// BK=64 GEMM: C = scale*(A.B^T)+bias (or p'=exp(scale*.) with EXPSUM).
// 128x128 tile, 16x16x32 bf16 MFMA, global_load_lds w=16, GROUP_M=8 swizzle,
// mod-8 LDS chunk-rotation (verified conflict-free R6-R8).
// WAVES=4: 256 thr, wave tile 64x64 (acc 4x4) -> 4 blocks/CU.
// WAVES=8: 512 thr, wave tile 32x64 (acc 2x4) -> 2 blocks/CU = 16 waves/CU,
//   exact 3-round schedule on the 1536-block QKV grid (R8 PV validated the
//   8-wave>4-wave residency effect).
template <bool HAS_BIAS, bool OUT_F32, int WAVES, bool VSPLIT, bool EXPSUM>
__global__ __launch_bounds__(WAVES * 64, 4) void gemm_bt(
    const bf16* __restrict__ A, const bf16* __restrict__ B,
    void* __restrict__ Cv, const bf16* __restrict__ bias,
    bf16* __restrict__ vt, float* __restrict__ rowsum,
    int K, long lda, long ldb, long ldc, float scale,
    long strideA, long strideB, long strideC)
{
    constexpr int BK = 64;
    constexpr int MI = (WAVES == 4) ? 4 : 2;
    constexpr int NCH = (WAVES == 4) ? 4 : 2;     // gload issues per matrix
    constexpr int RSTEP = WAVES * 8;              // rows per issue
    constexpr int LSTEP = WAVES * 64 * 8;         // LDS elems per issue

    __shared__ bf16 As[128 * BK];  // 16 KB
    __shared__ bf16 Bs[128 * BK];  // 16 KB

    const int tid  = threadIdx.x;
    const int wave = tid >> 6;
    const int lane = tid & 63;
    const int r16  = lane & 15;
    const int quad = lane >> 4;

    const long z = blockIdx.z;
    A += z * strideA;
    B += z * strideB;

    const int tX = gridDim.x;
    const int pid0 = blockIdx.y * tX + blockIdx.x;
    const int pid = xcd_remap(pid0, tX * (int)gridDim.y);
    const int groupSize = 8 * tX;
    const int gid = pid / groupSize;
    const int rem = pid % groupSize;
    const int tileM = (gid * 8 + (rem & 7)) * 128;
    const int tileN = (rem >> 3) * 128;

    const int waveM = (wave >> 1) * ((WAVES == 4) ? 64 : 32);
    const int waveN = (wave & 1) * 64;

    // Swizzled staging: phys slot p = tid + j*(WAVES*64); row = p>>3; logical
    // chunk c = ((p&7) - row) & 7, j-invariant (RSTEP is 0 mod 8).
    const int rS = tid >> 3;
    const int cOff = (((tid & 7) - (tid >> 3)) & 7) * 8;
    const bf16* Ag[NCH]; const bf16* Bg[NCH];
    #pragma unroll
    for (int j = 0; j < NCH; j++) {
        Ag[j] = A + (long)(tileM + rS + j * RSTEP) * lda + cOff;
        Bg[j] = B + (long)(tileN + rS + j * RSTEP) * ldb + cOff;
    }

    f32x4 acc[MI][4] = {};

    for (int k0 = 0; k0 < K; k0 += BK) {
        #pragma unroll
        for (int j = 0; j < NCH; j++) {
            gload_lds16(Ag[j], &As[tid * 8 + j * LSTEP]);
            gload_lds16(Bg[j], &Bs[tid * 8 + j * LSTEP]);
            Ag[j] += BK; Bg[j] += BK;
        }
        __syncthreads();

        #pragma unroll
        for (int ks = 0; ks < 2; ks++) {
            bf16x8 af[MI], bfv[4];
            #pragma unroll
            for (int i = 0; i < MI; i++) {
                const int row = waveM + i * 16 + r16;
                af[i] = *(const bf16x8*)
                    &As[row * 64 + ((ks * 4 + quad + row) & 7) * 8];
            }
            #pragma unroll
            for (int i = 0; i < 4; i++) {
                const int row = waveN + i * 16 + r16;
                bfv[i] = *(const bf16x8*)
                    &Bs[row * 64 + ((ks * 4 + quad + row) & 7) * 8];
            }
            #pragma unroll
            for (int mi = 0; mi < MI; mi++)
                #pragma unroll
                for (int ni = 0; ni < 4; ni++)
                    acc[mi][ni] = __builtin_amdgcn_mfma_f32_16x16x32_bf16(
                        af[mi], bfv[ni], acc[mi][ni], 0, 0, 0);
        }
        __syncthreads();
    }

    // C/D layout (m89/m91 verified): col = lane&15, row = quad*4 + r.
    const int crow0 = tileM + waveM + quad * 4;
    const int ccol0 = tileN + waveN + r16;

    if (EXPSUM) {
        float rs[MI][4];
        #pragma unroll
        for (int mi = 0; mi < MI; mi++)
            #pragma unroll
            for (int r = 0; r < 4; r++) rs[mi][r] = 0.0f;
        #pragma unroll
        for (int ni = 0; ni < 4; ni++) {
            const int col = ccol0 + ni * 16;
            #pragma unroll
            for (int mi = 0; mi < MI; mi++) {
                #pragma unroll
                for (int r = 0; r < 4; r++) {
                    const long row = crow0 + mi * 16 + r;
                    const float p = __expf(acc[mi][ni][r] * scale);
                    rs[mi][r] += p;
                    ((bf16*)Cv)[z * strideC + row * ldc + col] = (bf16)p;
                }
            }
        }
        #pragma unroll
        for (int mi = 0; mi < MI; mi++) {
            #pragma unroll
            for (int r = 0; r < 4; r++) {
                float s = rs[mi][r];
                s += __shfl_xor(s, 1, 64);
                s += __shfl_xor(s, 2, 64);
                s += __shfl_xor(s, 4, 64);
                s += __shfl_xor(s, 8, 64);
                if (r16 == 0)
                    atomicAdd(&rowsum[z * 2048 + crow0 + mi * 16 + r], s);
            }
        }
    } else if (VSPLIT && tileN >= 2048) {
        #pragma unroll
        for (int ni = 0; ni < 4; ni++) {
            const int col = ccol0 + ni * 16;
            const float bv = HAS_BIAS ? (float)bias[col] : 0.0f;
            const long colp = col - 2048;
            #pragma unroll
            for (int mi = 0; mi < MI; mi++) {
                const int grow = crow0 + mi * 16;
                const long bz = grow >> 11;
                const int srow = grow & 2047;
                bf16x4 o;
                #pragma unroll
                for (int r = 0; r < 4; r++)
                    o[r] = (bf16)(acc[mi][ni][r] * scale + bv);
                *(bf16x4*)&vt[(bz << 21) + colp * 2048 + srow] = o;
            }
        }
    } else {
        #pragma unroll
        for (int ni = 0; ni < 4; ni++) {
            const int col = ccol0 + ni * 16;
            const float bv = HAS_BIAS ? (float)bias[col] : 0.0f;
            #pragma unroll
            for (int mi = 0; mi < MI; mi++) {
                #pragma unroll
                for (int r = 0; r < 4; r++) {
                    const long row = crow0 + mi * 16 + r;
                    const float val = acc[mi][ni][r] * scale + bv;
                    if (OUT_F32) ((float*)Cv)[z * strideC + row * ldc + col] = val;
                    else         ((bf16*)Cv)[z * strideC + row * ldc + col] = (bf16)val;
                }
            }
        }
    }
}

// ---------------------------------------------------------------------------
// PV GEMM: 8 waves (512 thr), BK=128, 128x128 tile, wave tile 32x64.
// 64 KB LDS -> 2 blocks/CU = 16 waves/CU. out = (A.B^T) / rowsum[row].
// mod-16 chunk-rotation swizzle, j-invariant (32-row steps are 0 mod 16).
__global__ __launch_bounds__(512, 2) void gemm_pv(
    const bf16* __restrict__ A, const bf16* __restrict__ B,
    float* __restrict__ C, const float* __restrict__ rowsum,
    int K, long lda, long ldb, long ldc,
    long strideA, long strideB, long strideC)
{
    constexpr int BK = 128;
    __shared__ bf16 As[128 * BK];  // 32 KB
    __shared__ bf16 Bs[128 * BK];  // 32 KB

    const int tid  = threadIdx.x;
    const int wave = tid >> 6;
    const int lane = tid & 63;
    const int r16  = lane & 15;
    const int quad = lane >> 4;

    const long z = blockIdx.z;
    A += z * strideA;
    B += z * strideB;

    const int tX = gridDim.x;
    const int pid0 = blockIdx.y * tX + blockIdx.x;
    const int pid = xcd_remap(pid0, tX * (int)gridDim.y);
    const int groupSize = 8 * tX;
    const int gid = pid / groupSize;
    const int rem = pid % groupSize;
    const int tileM = (gid * 8 + (rem & 7)) * 128;
    const int tileN = (rem >> 3) * 128;

    const int waveM = (wave >> 1) * 32;
    const int waveN = (wave & 1) * 64;

    const int rS = tid >> 4;                              // 0..31
    const int cOff = (((tid & 15) - (tid >> 4)) & 15) * 8;
    const bf16* Ag = A + (long)(tileM + rS) * lda + cOff;
    const bf16* Bg = B + (long)(tileN + rS) * ldb + cOff;

    f32x4 acc[2][4] = {};

    for (int k0 = 0; k0 < K; k0 += BK) {
        #pragma unroll
        for (int j = 0; j < 4; j++) {
            gload_lds16(Ag + (long)j * 32 * lda, &As[(tid + j * 512) * 8]);
            gload_lds16(Bg + (long)j * 32 * ldb, &Bs[(tid + j * 512) * 8]);
        }
        Ag += BK; Bg += BK;
        __syncthreads();

        #pragma unroll
        for (int ks = 0; ks < 4; ks++) {
            bf16x8 af[2], bfv[4];
            #pragma unroll
            for (int i = 0; i < 2; i++) {
                const int row = waveM + i * 16 + r16;
                af[i] = *(const bf16x8*)
                    &As[row * 128 + ((ks * 4 + quad + row) & 15) * 8];
            }
            #pragma unroll
            for (int i = 0; i < 4; i++) {
                const int row = waveN + i * 16 + r16;
                bfv[i] = *(const bf16x8*)
                    &Bs[row * 128 + ((ks * 4 + quad + row) & 15) * 8];
            }
            #pragma unroll
            for (int mi = 0; mi < 2; mi++)
                #pragma unroll
                for (int ni = 0; ni < 4; ni++)
                    acc[mi][ni] = __builtin_amdgcn_mfma_f32_16x16x32_bf16(
                        af[mi], bfv[ni], acc[mi][ni], 0, 0, 0);
        }
        __syncthreads();
    }

    const int crow0 = tileM + waveM + quad * 4;
    const int ccol0 = tileN + waveN + r16;
    float inv[2][4];
    #pragma unroll
    for (int mi = 0; mi < 2; mi++)
        #pragma unroll
        for (int r = 0; r < 4; r++)
            inv[mi][r] = 1.0f / rowsum[z * 2048 + crow0 + mi * 16 + r];
    #pragma unroll
    for (int ni = 0; ni < 4; ni++) {
        const int col = ccol0 + ni * 16;
        #pragma unroll
        for (int mi = 0; mi < 2; mi++)
            #pragma unroll
            for (int r = 0; r < 4; r++) {
                const long row = crow0 + mi * 16 + r;
                C[z * strideC + row * ldc + col] = acc[mi][ni][r] * inv[mi][r];
            }
    }
}

extern "C" void kernel_launch(void* const* d_in, const int* in_sizes, int n_in,
                              void* d_out, int out_size, void* d_ws, size_t ws_size,
                              hipStream_t stream) {
    constexpr int B = 4, S = 2048, D = 1024, N = 1024;
    constexpr long MS = (long)B * S;  // 8192

    const void* X  = d_in[0];
    const void* Wq = d_in[1];
    const void* bq = d_in[2];
    const void* Wk = d_in[3];
    const void* bk = d_in[4];
    const void* Wv = d_in[5];
    const void* bv = d_in[6];

    // workspace layout (~120 MB)
    char* w = (char*)d_ws;
    bf16*  Xb = (bf16*)w;                w += MS * D * sizeof(bf16);          // 16 MB
    bf16*  wt = (bf16*)w;                w += 3L * D * N * sizeof(bf16);      // 6 MB
    bf16*  bb = (bf16*)w;                w += 3L * N * sizeof(bf16) + 512;
    float* rowsum = (float*)w;           w += MS * sizeof(float);             // 32 KB
    bf16*  qkv = (bf16*)w;               w += MS * 3L * N * sizeof(bf16);     // 48 MB
    bf16*  vt = (bf16*)w;                w += MS * N * sizeof(bf16);          // 16 MB
    bf16*  sc = (bf16*)w;                                                    // 32 MB

    bf16* q = qkv;            // cols 0..1023 of [8192,3072]
    bf16* k = qkv + N;        // cols 1024..2047 (V cols go straight to vt)

    // 1) prep: detect + convert X/biases + transpose weights + zero rowsum
    prep<<<7188, 256, 0, stream>>>(X, Wq, Wk, Wv, bq, bk, bv, Xb, wt, bb, rowsum);

    // 2) fused QKV (8-wave blocks): q,k -> qkv; V -> vt transposed.
    //    1536 blocks @ 2/CU = exact 3 rounds, 16 waves/CU. XCD chunk = 192
    //    blocks = exactly one GROUP_M group (M-tiles 0-7 x all 24 N-tiles).
    gemm_bt<true, false, 8, true, false><<<dim3(3 * N / 128, MS / 128, 1), 512, 0, stream>>>(
        Xb, wt, qkv, bb, vt, nullptr, D, D, D, 3L * N, 1.0f, 0, 0, 0);

    // 3) p' = exp(q.k^T / 32) -> bf16 sc, + atomic row sums (4-wave:
    //    1024 blocks @ 4/CU = exactly 1 round). Per-XCD working set 3 MB -> L2-fits.
    gemm_bt<false, false, 4, false, true><<<dim3(S / 128, S / 128, B), 256, 0, stream>>>(
        q, k, sc, nullptr, nullptr, rowsum, D, 3L * N, 3L * N, S, 0.03125f,
        (long)S * 3 * N, (long)S * 3 * N, (long)S * S);

    // 4) out = (p' . vt^T) / rowsum -> f32 d_out (8-wave BK=128 PV)
    gemm_pv<<<dim3(N / 128, S / 128, B), 512, 0, stream>>>(
        sc, vt, (float*)d_out, rowsum, S, S, S, N,
        (long)S * S, (long)N * S, (long)S * N);
}